// Round 13
// baseline (241.075 us; speedup 1.0000x reference)
//
#include <hip/hip_runtime.h>
#include <hip/hip_bf16.h>

#define B_ 4
#define T_ 4096
#define S_ 1024
#define HID_ 1024
#define CTX_ 768
#define EMB_ 1024
#define H_ 16
#define D_ 64

// Q pre-scale: (1/sqrt(D)) * log2(e) so softmax runs in exp2 domain.
#define QSCALE 0.18033688011112042f

typedef __attribute__((ext_vector_type(8))) short short8;
typedef __attribute__((ext_vector_type(4))) float f32x4;
typedef __attribute__((ext_vector_type(4))) unsigned short us4;
typedef unsigned short ushort_t;

__device__ inline ushort_t f2b(float f) {
  union { float f; unsigned u; } x; x.f = f;
  return (ushort_t)((x.u + 0x7fffu + ((x.u >> 16) & 1u)) >> 16);
}
__device__ inline unsigned cvtpk2(float a, float b) {
  __hip_bfloat162 h = __float22bfloat162_rn(float2{a, b});
  union { __hip_bfloat162 h; unsigned u; } c; c.h = h; return c.u;
}
__device__ inline ushort_t f2b_fast(float f) {
  __hip_bfloat16 h = __float2bfloat16(f);
  union { __hip_bfloat16 h; ushort_t u; } c; c.h = h; return c.u;
}

using gu32p = const __attribute__((address_space(1))) unsigned int*;
using lu32p = __attribute__((address_space(3))) unsigned int*;
__device__ inline void gload16(const ushort_t* g, ushort_t* l) {
  __builtin_amdgcn_global_load_lds((gu32p)(const void*)g, (lu32p)(void*)l, 16, 0, 0);
}

// ---- prep: weight transposes only (ctx conv fused into proj2) ----
// W[K][1024] f32 -> Wt[1024][K] bf16, 32x32 tile #tile
__device__ inline void convT_body(const float* __restrict__ W, ushort_t* __restrict__ Wt,
                                  int K, int tile, int tid, float (*Ls)[33]) {
  const int n0 = (tile & 31) * 32, k0 = (tile >> 5) * 32;
  const int r = tid >> 3, c4 = (tid & 7) * 4;
  const float4 v = *(const float4*)&W[(size_t)(k0 + r) * 1024 + n0 + c4];
  Ls[r][c4] = v.x; Ls[r][c4 + 1] = v.y; Ls[r][c4 + 2] = v.z; Ls[r][c4 + 3] = v.w;
  __syncthreads();
  us4 o;
  o.x = f2b_fast(Ls[c4][r]);     o.y = f2b_fast(Ls[c4 + 1][r]);
  o.z = f2b_fast(Ls[c4 + 2][r]); o.w = f2b_fast(Ls[c4 + 3][r]);
  *(us4*)&Wt[(size_t)(n0 + r) * K + k0 + c4] = o;
}

__global__ __launch_bounds__(256) void prepA(
    const float* __restrict__ Wq, const float* __restrict__ Wk,
    const float* __restrict__ Wv, const float* __restrict__ Wo,
    ushort_t* __restrict__ WqT, ushort_t* __restrict__ WkvT,
    ushort_t* __restrict__ WoT)
{
  __shared__ float Ls[32][33];
  const int tid = threadIdx.x;
  int blk = (int)blockIdx.x;
  if (blk < 1024) { convT_body(Wq, WqT, 1024, blk, tid, Ls); return; }
  blk -= 1024;
  if (blk < 768)  { convT_body(Wk, WkvT, 768, blk, tid, Ls); return; }
  blk -= 768;
  if (blk < 768)  { convT_body(Wv, WkvT + (size_t)1024 * 768, 768, blk, tid, Ls); return; }
  blk -= 768;
  convT_body(Wo, WoT, 1024, blk, tid, Ls);
}

// ==== proj2: merged Q-proj (even blocks) + KV-proj (odd blocks) ====

// ---- Q body: 256x256, 4-slot ring, A read f32 reg-staged (tokens) ----
__device__ __forceinline__ void q_body(
    int lin, int tid, ushort_t* L,
    const float* __restrict__ Af, const ushort_t* __restrict__ Bt,
    ushort_t* __restrict__ Cp)
{
  constexpr int Kd = 1024, NT = 32, N = EMB_;
  const int lane = tid & 63, wid = tid >> 6;
  const int lr = lane & 15, lg = lane >> 4;
  const int wm = wid >> 2, wn = wid & 3;

  const int swz = (lin & 7) * 32 + (lin >> 3);   // 256 Q-blocks, XCD swizzle
  const int bm = swz >> 2, bn = swz & 3;

  const int sr = tid >> 2;
  const int csrc = (tid & 3) ^ ((sr >> 1) & 3);
  const float* gA = Af + (size_t)(bm * 256 + sr) * Kd + csrc * 8;
  const ushort_t* gB = Bt + (size_t)(bn * 256 + sr) * Kd + csrc * 8;
  const size_t half = (size_t)128 * Kd;
  ushort_t* const dA = L + tid * 8;
  ushort_t* const dB = L + 8192 + tid * 8;

  f32x4 acc[8][4] = {};
  float4 ra0[4], ra1[4];

#define ALOADF(c, RS) do { const int k0_ = (c) << 5;      \
    RS[0] = *(const float4*)(gA + k0_);                   \
    RS[1] = *(const float4*)(gA + k0_ + 4);               \
    RS[2] = *(const float4*)(gA + k0_ + half);            \
    RS[3] = *(const float4*)(gA + k0_ + half + 4);        \
  } while (0)

#define AWRITE(c, RS) do { const int slot_ = ((c) & 3) * 16384;  \
    uint4 u0, u1;                                                \
    u0.x = cvtpk2(RS[0].x, RS[0].y); u0.y = cvtpk2(RS[0].z, RS[0].w); \
    u0.z = cvtpk2(RS[1].x, RS[1].y); u0.w = cvtpk2(RS[1].z, RS[1].w); \
    u1.x = cvtpk2(RS[2].x, RS[2].y); u1.y = cvtpk2(RS[2].z, RS[2].w); \
    u1.z = cvtpk2(RS[3].x, RS[3].y); u1.w = cvtpk2(RS[3].z, RS[3].w); \
    *(uint4*)(dA + slot_) = u0;                                  \
    *(uint4*)(dA + slot_ + 4096) = u1;                           \
  } while (0)

#define BSTAGE(c) do { const int slot_ = ((c) & 3) * 16384; const int k0_ = (c) << 5; \
    gload16(gB + k0_, dB + slot_);                      \
    gload16(gB + k0_ + half, dB + slot_ + 4096);        \
  } while (0)

#define COMPUTE(c) do {                                                  \
    const ushort_t* As_ = L + ((c) & 3) * 16384;                         \
    const ushort_t* Bs_ = As_ + 8192;                                    \
    short8 af[8], bf[4];                                                 \
    _Pragma("unroll")                                                    \
    for (int m = 0; m < 8; ++m) {                                        \
      const int row = wm * 128 + m * 16 + lr;                            \
      af[m] = *(const short8*)&As_[row * 32 + (lg ^ ((row >> 1) & 3)) * 8]; \
    }                                                                    \
    _Pragma("unroll")                                                    \
    for (int n = 0; n < 4; ++n) {                                        \
      const int row = wn * 64 + n * 16 + lr;                             \
      bf[n] = *(const short8*)&Bs_[row * 32 + (lg ^ ((row >> 1) & 3)) * 8]; \
    }                                                                    \
    __builtin_amdgcn_s_setprio(1);                                       \
    _Pragma("unroll")                                                    \
    for (int m = 0; m < 8; ++m)                                          \
      _Pragma("unroll")                                                  \
      for (int n = 0; n < 4; ++n)                                        \
        acc[m][n] = __builtin_amdgcn_mfma_f32_16x16x32_bf16(af[m], bf[n], acc[m][n], 0, 0, 0); \
    __builtin_amdgcn_s_setprio(0);                                       \
  } while (0)

#define ENDBAR do {                                        \
    asm volatile("s_waitcnt lgkmcnt(0)" ::: "memory");     \
    __builtin_amdgcn_s_barrier();                          \
    __builtin_amdgcn_sched_barrier(0);                     \
  } while (0)

  {
    float4 p0[4], p1[4], p2[4];
    ALOADF(0, p0); ALOADF(1, p1); ALOADF(2, p2);
    AWRITE(0, p0); AWRITE(1, p1); AWRITE(2, p2);
    BSTAGE(0); BSTAGE(1); BSTAGE(2);
    ALOADF(3, ra1);
    asm volatile("s_waitcnt vmcnt(4)" ::: "memory");  // B0,B1 landed (B2+A3 in flight)
    ENDBAR;
  }

  for (int t = 0; t < NT - 2; t += 2) {
    if (t + 3 < NT) { AWRITE(t + 3, ra1); BSTAGE(t + 3); }
    if (t + 4 < NT) ALOADF(t + 4, ra0);
    COMPUTE(t);
    ENDBAR;
    if (t + 4 < NT) { AWRITE(t + 4, ra0); BSTAGE(t + 4); }
    if (t + 5 < NT) ALOADF(t + 5, ra1);
    COMPUTE(t + 1);
    ENDBAR;
  }
  // tail: drain all staging loads (fixes latent race on chunks NT-2, NT-1)
  asm volatile("s_waitcnt vmcnt(0)" ::: "memory");
  __builtin_amdgcn_s_barrier();
  __builtin_amdgcn_sched_barrier(0);
  COMPUTE(NT - 2);
  COMPUTE(NT - 1);
#undef ALOADF
#undef AWRITE
#undef BSTAGE
#undef COMPUTE
#undef ENDBAR

  const int row0 = bm * 256 + wm * 128 + lg * 4;
  const int col0 = bn * 256 + wn * 64 + lr;
#pragma unroll
  for (int m = 0; m < 8; ++m)
#pragma unroll
    for (int n = 0; n < 4; ++n) {
      const int col = col0 + n * 16;
#pragma unroll
      for (int i = 0; i < 4; ++i)
        Cp[(size_t)(row0 + m * 16 + i) * N + col] = f2b(acc[m][n][i] * QSCALE);
    }
}

// ---- KV body: 128x256, ring-3, A read f32 reg-staged (context), dual epilogue ----
__device__ __forceinline__ void kv_body(
    int lin, int tid, ushort_t* L,
    const float* __restrict__ Ctx, const ushort_t* __restrict__ Bt,
    ushort_t* __restrict__ Kb, ushort_t* __restrict__ Vtb)
{
  constexpr int Kd = CTX_, NT = CTX_ / 32;   // 24 chunks
  const int lane = tid & 63, wid = tid >> 6;
  const int lr = lane & 15, lg = lane >> 4;
  const int wm = wid >> 2, wn = wid & 3;

  const int swz = (lin & 7) * 32 + (lin >> 3);
  const int bm = swz >> 3, bn = swz & 7;

  const int sr = tid >> 2;
  const int csrc = (tid & 3) ^ ((sr >> 1) & 3);
  const float* gA = Ctx + (size_t)(bm * 128 + sr) * Kd + csrc * 8;
  const ushort_t* gB = Bt + (size_t)(bn * 256 + sr) * Kd + csrc * 8;
  const size_t halfB = (size_t)128 * Kd;

  f32x4 acc[4][4] = {};
  float4 ra0[2], ra1[2];

#define ALOADF2(c, RS) do { const int k0_ = (c) << 5;     \
    RS[0] = *(const float4*)(gA + k0_);                   \
    RS[1] = *(const float4*)(gA + k0_ + 4);               \
  } while (0)

#define AWRITE2(c, RS) do { const int slot_ = ((c) % 3) * 12288;  \
    uint4 u0;                                                     \
    u0.x = cvtpk2(RS[0].x, RS[0].y); u0.y = cvtpk2(RS[0].z, RS[0].w); \
    u0.z = cvtpk2(RS[1].x, RS[1].y); u0.w = cvtpk2(RS[1].z, RS[1].w); \
    *(uint4*)(L + slot_ + tid * 8) = u0;                          \
  } while (0)

#define BSTAGE2(c) do { const int slot_ = ((c) % 3) * 12288; const int k0_ = (c) << 5; \
    gload16(gB + k0_, L + slot_ + 4096 + tid * 8);              \
    gload16(gB + k0_ + halfB, L + slot_ + 8192 + tid * 8);      \
  } while (0)

#define COMPUTEKV(c) do {                                                \
    const ushort_t* As_ = L + ((c) % 3) * 12288;                         \
    const ushort_t* Bs_ = As_ + 4096;                                    \
    short8 af[4], bf[4];                                                 \
    _Pragma("unroll")                                                    \
    for (int m = 0; m < 4; ++m) {                                        \
      const int row = wm * 64 + m * 16 + lr;                             \
      af[m] = *(const short8*)&As_[row * 32 + (lg ^ ((row >> 1) & 3)) * 8]; \
    }                                                                    \
    _Pragma("unroll")                                                    \
    for (int n = 0; n < 4; ++n) {                                        \
      const int row = wn * 64 + n * 16 + lr;                             \
      bf[n] = *(const short8*)&Bs_[row * 32 + (lg ^ ((row >> 1) & 3)) * 8]; \
    }                                                                    \
    __builtin_amdgcn_s_setprio(1);                                       \
    _Pragma("unroll")                                                    \
    for (int m = 0; m < 4; ++m)                                          \
      _Pragma("unroll")                                                  \
      for (int n = 0; n < 4; ++n)                                        \
        acc[m][n] = __builtin_amdgcn_mfma_f32_16x16x32_bf16(af[m], bf[n], acc[m][n], 0, 0, 0); \
    __builtin_amdgcn_s_setprio(0);                                       \
  } while (0)

#define ENDBAR2 do {                                       \
    asm volatile("s_waitcnt lgkmcnt(0)" ::: "memory");     \
    __builtin_amdgcn_s_barrier();                          \
    __builtin_amdgcn_sched_barrier(0);                     \
  } while (0)

  {
    float4 p0[2], p1[2];
    ALOADF2(0, p0); ALOADF2(1, p1);
    AWRITE2(0, p0); AWRITE2(1, p1);
    BSTAGE2(0); BSTAGE2(1);
    ALOADF2(2, ra0);
    asm volatile("s_waitcnt vmcnt(2)" ::: "memory");  // B0,B1 landed (A2 in flight)
    ENDBAR2;
  }

  for (int t = 0; t < NT - 2; t += 2) {
    AWRITE2(t + 2, ra0); BSTAGE2(t + 2);
    if (t + 3 < NT) ALOADF2(t + 3, ra1);
    COMPUTEKV(t);
    ENDBAR2;
    AWRITE2(t + 3, ra1); BSTAGE2(t + 3);
    if (t + 4 < NT) ALOADF2(t + 4, ra0);
    COMPUTEKV(t + 1);
    ENDBAR2;
  }
  asm volatile("s_waitcnt vmcnt(0)" ::: "memory");
  __builtin_amdgcn_s_barrier();
  __builtin_amdgcn_sched_barrier(0);
  COMPUTEKV(NT - 2);
  COMPUTEKV(NT - 1);
#undef ALOADF2
#undef AWRITE2
#undef BSTAGE2
#undef COMPUTEKV
#undef ENDBAR2

  const int row0 = bm * 128 + wm * 64 + lg * 4;
  const int col0 = bn * 256 + wn * 64 + lr;

  if (col0 < 1024) {       // K half (block-uniform: bn < 4)
#pragma unroll
    for (int m = 0; m < 4; ++m)
#pragma unroll
      for (int n = 0; n < 4; ++n) {
        const int col = col0 + n * 16;
#pragma unroll
        for (int i = 0; i < 4; ++i)
          Kb[(size_t)(row0 + m * 16 + i) * EMB_ + col] = f2b_fast(acc[m][n][i]);
      }
  } else {                 // V half -> V^T [B][H][D][S]
#pragma unroll
    for (int m = 0; m < 4; ++m) {
      const int rbase = row0 + m * 16;
      const int bb = rbase >> 10;
      const int s0 = rbase & (S_ - 1);
#pragma unroll
      for (int n = 0; n < 4; ++n) {
        const int vc = col0 + n * 16 - 1024;
        const int hh = vc >> 6, dd = vc & 63;
        us4 o;
        o.x = f2b_fast(acc[m][n][0]); o.y = f2b_fast(acc[m][n][1]);
        o.z = f2b_fast(acc[m][n][2]); o.w = f2b_fast(acc[m][n][3]);
        *(us4*)&Vtb[(((size_t)bb * H_ + hh) * D_ + dd) * S_ + s0] = o;
      }
    }
  }
}

__global__ __launch_bounds__(512) void proj2(
    const float* __restrict__ tokens, const float* __restrict__ ctx,
    const ushort_t* __restrict__ WqT, const ushort_t* __restrict__ WkvT,
    ushort_t* __restrict__ Qb, ushort_t* __restrict__ Kb,
    ushort_t* __restrict__ Vtb)
{
  extern __shared__ ushort_t L[];
  const int blk = (int)blockIdx.x;
  if (blk & 1) kv_body(blk >> 1, threadIdx.x, L, ctx, WkvT, Kb, Vtb);
  else         q_body(blk >> 1, threadIdx.x, L, tokens, WqT, Qb);
}

// ---- gemm256p: O-proj, 256x256, ring-3 x 4-phase fine interleave ----
__global__ __launch_bounds__(512) void gemm256p(
    const ushort_t* __restrict__ A, const ushort_t* __restrict__ Bt,
    float* __restrict__ Cp, const float* __restrict__ bias,
    int M, int Kd, int N)
{
  extern __shared__ ushort_t L[];   // 3 slots x 16384 ushorts (A 8192 | B 8192)
  const int tid = threadIdx.x;
  const int lane = tid & 63, wid = tid >> 6;
  const int lr = lane & 15, lg = lane >> 4;
  const int wm = wid >> 2, wn = wid & 3;

  const int cpx = (int)gridDim.x >> 3;
  const int lin = (int)blockIdx.x;
  const int swz = (lin & 7) * cpx + (lin >> 3);
  const int nbn = N >> 8;
  const int bm = swz / nbn, bn = swz % nbn;

  const int sr = tid >> 2;
  const int csrc = (tid & 3) ^ ((sr >> 1) & 3);
  const ushort_t* gA = A + (size_t)(bm * 256 + sr) * Kd + csrc * 8;
  const ushort_t* gB = Bt + (size_t)(bn * 256 + sr) * Kd + csrc * 8;
  const size_t half = (size_t)128 * Kd;

  f32x4 acc[8][4] = {};
  const int NT = Kd >> 5;

#define STAGEQ(c, q) do {                                            \
    const int k0_ = (c) << 5;                                        \
    ushort_t* s_ = L + ((c) % 3) * 16384 + (q) * 4096 + tid * 8;     \
    if ((q) == 0)      gload16(gA + k0_, s_);                        \
    else if ((q) == 1) gload16(gA + k0_ + half, s_);                 \
    else if ((q) == 2) gload16(gB + k0_, s_);                        \
    else               gload16(gB + k0_ + half, s_);                 \
  } while (0)

#pragma unroll
  for (int q = 0; q < 4; ++q) STAGEQ(0, q);
#pragma unroll
  for (int q = 0; q < 4; ++q) STAGEQ(1, q);
  asm volatile("s_waitcnt vmcnt(4)" ::: "memory");
  __builtin_amdgcn_s_barrier();
  __builtin_amdgcn_sched_barrier(0);

  for (int t = 0; t < NT; ++t) {
    const ushort_t* As_ = L + (t % 3) * 16384;
    const ushort_t* Bs_ = As_ + 8192;
    const bool st = (t + 2 < NT);
    short8 bf[4];
#pragma unroll
    for (int q = 0; q < 4; ++q) {
      if (q == 0) {
#pragma unroll
        for (int n = 0; n < 4; ++n) {
          const int row = wn * 64 + n * 16 + lr;
          bf[n] = *(const short8*)&Bs_[row * 32 + (lg ^ ((row >> 1) & 3)) * 8];
        }
      }
      const int r0 = wm * 128 + (2 * q) * 16 + lr;
      const int r1 = r0 + 16;
      const short8 af0 = *(const short8*)&As_[r0 * 32 + (lg ^ ((r0 >> 1) & 3)) * 8];
      const short8 af1 = *(const short8*)&As_[r1 * 32 + (lg ^ ((r1 >> 1) & 3)) * 8];
      if (st) STAGEQ(t + 2, q);
      __builtin_amdgcn_s_barrier();
      asm volatile("s_waitcnt lgkmcnt(0)" ::: "memory");
      __builtin_amdgcn_sched_barrier(0);
      __builtin_amdgcn_s_setprio(1);
#pragma unroll
      for (int n = 0; n < 4; ++n)
        acc[2 * q][n] = __builtin_amdgcn_mfma_f32_16x16x32_bf16(af0, bf[n], acc[2 * q][n], 0, 0, 0);
#pragma unroll
      for (int n = 0; n < 4; ++n)
        acc[2 * q + 1][n] = __builtin_amdgcn_mfma_f32_16x16x32_bf16(af1, bf[n], acc[2 * q + 1][n], 0, 0, 0);
      __builtin_amdgcn_s_setprio(0);
      if (q == 3 && t < NT - 1) {
        if (st) asm volatile("s_waitcnt vmcnt(4)" ::: "memory");
        else    asm volatile("s_waitcnt vmcnt(0)" ::: "memory");
      }
      __builtin_amdgcn_s_barrier();
      __builtin_amdgcn_sched_barrier(0);
    }
  }
#undef STAGEQ

  const int row0 = bm * 256 + wm * 128 + lg * 4;
  const int col0 = bn * 256 + wn * 64 + lr;
#pragma unroll
  for (int n = 0; n < 4; ++n) {
    const int col = col0 + n * 16;
    const float bv = bias[col];
#pragma unroll
    for (int m = 0; m < 8; ++m)
#pragma unroll
      for (int i = 0; i < 4; ++i)
        Cp[(size_t)(row0 + m * 16 + i) * N + col] = acc[m][n][i] + bv;
  }
}

// ---- flash attention v8 (best: 115.4 µs): QBLK=256, 8 waves x 32 rows,
//      SBLK=64, swapped QK^T, no-max exp2 softmax, l via ones-MFMA,
//      ring-3 K/V with counted vmcnt(2), shared per-wave Ps ----
__global__ __launch_bounds__(512) void attn_v8(
    const ushort_t* __restrict__ Q, const ushort_t* __restrict__ K,
    const ushort_t* __restrict__ Vt, ushort_t* __restrict__ C)
{
  extern __shared__ ushort_t SM[];
  const int tid = threadIdx.x;
  const int lane = tid & 63, w = tid >> 6;
  const int lr = lane & 15, lg = lane >> 4;

  const int bid = (int)blockIdx.x;
  const int g = (bid & 7) | (((bid >> 3) >> 4) << 3);
  const int tb = (bid >> 3) & 15;
  const int h = g & 15, b = g >> 4;
  const int t0 = tb * 256;

  short8 qf[2][2];
#pragma unroll
  for (int qs = 0; qs < 2; ++qs) {
    const size_t qrow = (size_t)b * T_ + t0 + w * 32 + qs * 16 + lr;
    const ushort_t* qp = Q + qrow * EMB_ + h * 64;
    qf[qs][0] = *(const short8*)(qp + lg * 8);
    qf[qs][1] = *(const short8*)(qp + 32 + lg * 8);
  }

  short8 ones;
#pragma unroll
  for (int j = 0; j < 8; ++j) ones[j] = (short)0x3F80;

  f32x4 o[2][4] = {};
  f32x4 lacc[2] = {};

  const int srow = tid >> 3, schunk = tid & 7;
  const int sswz = schunk ^ (srow & 7);
  const ushort_t* kg = K + ((size_t)b * S_ + srow) * EMB_ + h * 64 + sswz * 8;
  const ushort_t* vg = Vt + (((size_t)b * H_ + h) * D_ + srow) * S_ + sswz * 8;
  ushort_t* Psw = SM + 24576 + w * 1152;

  gload16(kg, SM + tid * 8);
  gload16(vg, SM + 12288 + tid * 8);
  gload16(kg + (size_t)64 * EMB_, SM + 4096 + tid * 8);
  gload16(vg + 64, SM + 12288 + 4096 + tid * 8);

  int cur = 0, sls = 2;
  for (int st = 0; st < 16; ++st) {
    if (st < 15) asm volatile("s_waitcnt vmcnt(2)" ::: "memory");
    else         asm volatile("s_waitcnt vmcnt(0)" ::: "memory");
    __builtin_amdgcn_s_barrier();
    __builtin_amdgcn_sched_barrier(0);
    if (st + 2 < 16) {
      gload16(kg + (size_t)(st + 2) * 64 * EMB_, SM + sls * 4096 + tid * 8);
      gload16(vg + (st + 2) * 64, SM + 12288 + sls * 4096 + tid * 8);
    }
    const ushort_t* Ksb = SM + cur * 4096;
    const ushort_t* Vsb = SM + 12288 + cur * 4096;

    f32x4 sacc[2][4] = {};
    __builtin_amdgcn_s_setprio(1);
#pragma unroll
    for (int c = 0; c < 4; ++c) {
      const int krow = c * 16 + lr;
      const int sw = krow & 7;
      const short8 ka0 = *(const short8*)&Ksb[krow * 64 + ((lg ^ sw) * 8)];
      const short8 ka1 = *(const short8*)&Ksb[krow * 64 + (((4 + lg) ^ sw) * 8)];
#pragma unroll
      for (int qs = 0; qs < 2; ++qs) {
        sacc[qs][c] = __builtin_amdgcn_mfma_f32_16x16x32_bf16(ka0, qf[qs][0], sacc[qs][c], 0, 0, 0);
        sacc[qs][c] = __builtin_amdgcn_mfma_f32_16x16x32_bf16(ka1, qf[qs][1], sacc[qs][c], 0, 0, 0);
      }
    }
    __builtin_amdgcn_s_setprio(0);

    short8 pa[2][2];
#pragma unroll
    for (int qs = 0; qs < 2; ++qs) {
#pragma unroll
      for (int c = 0; c < 4; ++c) {
        uint2 pk;
        pk.x = cvtpk2(exp2f(sacc[qs][c][0]), exp2f(sacc[qs][c][1]));
        pk.y = cvtpk2(exp2f(sacc[qs][c][2]), exp2f(sacc[qs][c][3]));
        *(uint2*)&Psw[lr * 72 + c * 16 + lg * 4] = pk;
      }
      pa[qs][0] = *(const short8*)&Psw[lr * 72 + lg * 8];
      pa[qs][1] = *(const short8*)&Psw[lr * 72 + 32 + lg * 8];
    }

    __builtin_amdgcn_s_setprio(1);
#pragma unroll
    for (int sh = 0; sh < 2; ++sh) {
#pragma unroll
      for (int dc = 0; dc < 4; ++dc) {
        const int vrow = dc * 16 + lr;
        const int vsw = vrow & 7;
        const short8 vb = *(const short8*)&Vsb[vrow * 64 + (((sh * 4 + lg) ^ vsw) * 8)];
        o[0][dc] = __builtin_amdgcn_mfma_f32_16x16x32_bf16(pa[0][sh], vb, o[0][dc], 0, 0, 0);
        o[1][dc] = __builtin_amdgcn_mfma_f32_16x16x32_bf16(pa[1][sh], vb, o[1][dc], 0, 0, 0);
      }
      lacc[0] = __builtin_amdgcn_mfma_f32_16x16x32_bf16(pa[0][sh], ones, lacc[0], 0, 0, 0);
      lacc[1] = __builtin_amdgcn_mfma_f32_16x16x32_bf16(pa[1][sh], ones, lacc[1], 0, 0, 0);
    }
    __builtin_amdgcn_s_setprio(0);

    cur = (cur == 2) ? 0 : cur + 1;
    sls = (sls == 2) ? 0 : sls + 1;
  }

#pragma unroll
  for (int qs = 0; qs < 2; ++qs) {
#pragma unroll
    for (int i = 0; i < 4; ++i) {
      const float li = 1.0f / lacc[qs][i];
      const size_t trow = (size_t)b * T_ + t0 + w * 32 + qs * 16 + lg * 4 + i;
#pragma unroll
      for (int dc = 0; dc < 4; ++dc)
        C[trow * EMB_ + h * 64 + dc * 16 + lr] = f2b_fast(o[qs][dc][i] * li);
    }
  }
}

extern "C" void kernel_launch(void* const* d_in, const int* in_sizes, int n_in,
                              void* d_out, int out_size, void* d_ws, size_t ws_size,
                              hipStream_t stream) {
  const float* tokens  = (const float*)d_in[0];
  const float* context = (const float*)d_in[1];
  const float* Wq = (const float*)d_in[2];
  const float* Wk = (const float*)d_in[3];
  const float* Wv = (const float*)d_in[4];
  const float* Wo = (const float*)d_in[5];
  const float* bo = (const float*)d_in[6];
  float* out = (float*)d_out;

  // d_out lower half holds Qb until O-proj overwrites d_out:
  ushort_t* Qb  = (ushort_t*)d_out;
  // ws: Kb | Vtb | Cb (attn out) | WqT | WkvT | WoT
  ushort_t* Kb   = (ushort_t*)d_ws;
  ushort_t* Vtb  = Kb + (size_t)B_ * S_ * EMB_;
  ushort_t* Cb   = Vtb + (size_t)B_ * S_ * EMB_;
  ushort_t* WqT  = Cb + (size_t)B_ * T_ * EMB_;
  ushort_t* WkvT = WqT + (size_t)EMB_ * HID_;
  ushort_t* WoT  = WkvT + (size_t)EMB_ * 2 * CTX_;

  // 1. weight transposes (Wq^T, Wk^T, Wv^T, Wo^T)
  prepA<<<3584, 256, 0, stream>>>(Wq, Wk, Wv, Wo, WqT, WkvT, WoT);
  // 2. merged Q-proj (f32 tokens) + KV-proj (f32 context), interleaved blocks
  proj2<<<512, 512, 131072, stream>>>(tokens, context, WqT, WkvT, Qb, Kb, Vtb);
  // 3. attention -> ctx bf16 (Cb)
  attn_v8<<<dim3((T_ / 256) * H_ * B_), 512, 67584, stream>>>(Qb, Kb, Vtb, Cb);
  // 4. O-proj + bias -> f32 out, 4-phase fine-interleaved ring-3
  gemm256p<<<dim3((B_ * T_ / 256) * (HID_ / 256)), 512, 98304, stream>>>(
      Cb, WoT, out, bo, B_ * T_, EMB_, HID_);
}

// Round 14
// 224.302 us; speedup vs baseline: 1.0748x; 1.0748x over previous
//
#include <hip/hip_runtime.h>
#include <hip/hip_bf16.h>

#define B_ 4
#define T_ 4096
#define S_ 1024
#define HID_ 1024
#define CTX_ 768
#define EMB_ 1024
#define H_ 16
#define D_ 64

// Q pre-scale: (1/sqrt(D)) * log2(e) so softmax runs in exp2 domain.
#define QSCALE 0.18033688011112042f

typedef __attribute__((ext_vector_type(8))) short short8;
typedef __attribute__((ext_vector_type(4))) float f32x4;
typedef __attribute__((ext_vector_type(4))) unsigned short us4;
typedef unsigned short ushort_t;

__device__ inline ushort_t f2b(float f) {
  union { float f; unsigned u; } x; x.f = f;
  return (ushort_t)((x.u + 0x7fffu + ((x.u >> 16) & 1u)) >> 16);
}
__device__ inline unsigned cvtpk2(float a, float b) {
  __hip_bfloat162 h = __float22bfloat162_rn(float2{a, b});
  union { __hip_bfloat162 h; unsigned u; } c; c.h = h; return c.u;
}
__device__ inline ushort_t f2b_fast(float f) {
  __hip_bfloat16 h = __float2bfloat16(f);
  union { __hip_bfloat16 h; ushort_t u; } c; c.h = h; return c.u;
}

using gu32p = const __attribute__((address_space(1))) unsigned int*;
using lu32p = __attribute__((address_space(3))) unsigned int*;
__device__ inline void gload16(const ushort_t* g, ushort_t* l) {
  __builtin_amdgcn_global_load_lds((gu32p)(const void*)g, (lu32p)(void*)l, 16, 0, 0);
}

// ---- prep: f32->bf16 convs (tokens, context) + all weight transposes ----
__device__ inline void conv_body(const float* __restrict__ in, ushort_t* __restrict__ out,
                                 int blk, int tid) {
  const size_t i = ((size_t)blk * 256 + tid) * 8;
  const float4 a = *(const float4*)(in + i);
  const float4 b = *(const float4*)(in + i + 4);
  uint4 u;
  u.x = cvtpk2(a.x, a.y); u.y = cvtpk2(a.z, a.w);
  u.z = cvtpk2(b.x, b.y); u.w = cvtpk2(b.z, b.w);
  *(uint4*)(out + i) = u;
}

// W[K][1024] f32 -> Wt[1024][K] bf16, 32x32 tile #tile
__device__ inline void convT_body(const float* __restrict__ W, ushort_t* __restrict__ Wt,
                                  int K, int tile, int tid, float (*Ls)[33]) {
  const int n0 = (tile & 31) * 32, k0 = (tile >> 5) * 32;
  const int r = tid >> 3, c4 = (tid & 7) * 4;
  const float4 v = *(const float4*)&W[(size_t)(k0 + r) * 1024 + n0 + c4];
  Ls[r][c4] = v.x; Ls[r][c4 + 1] = v.y; Ls[r][c4 + 2] = v.z; Ls[r][c4 + 3] = v.w;
  __syncthreads();
  us4 o;
  o.x = f2b_fast(Ls[c4][r]);     o.y = f2b_fast(Ls[c4 + 1][r]);
  o.z = f2b_fast(Ls[c4 + 2][r]); o.w = f2b_fast(Ls[c4 + 3][r]);
  *(us4*)&Wt[(size_t)(n0 + r) * K + k0 + c4] = o;
}

__global__ __launch_bounds__(256) void prepA(
    const float* __restrict__ tokens, const float* __restrict__ context,
    const float* __restrict__ Wq, const float* __restrict__ Wk,
    const float* __restrict__ Wv, const float* __restrict__ Wo,
    ushort_t* __restrict__ Tok, ushort_t* __restrict__ CtxB,
    ushort_t* __restrict__ WqT, ushort_t* __restrict__ WkvT,
    ushort_t* __restrict__ WoT)
{
  __shared__ float Ls[32][33];
  const int tid = threadIdx.x;
  int blk = (int)blockIdx.x;
  if (blk < 8192) { conv_body(tokens, Tok, blk, tid); return; }
  blk -= 8192;
  if (blk < 1536) { conv_body(context, CtxB, blk, tid); return; }
  blk -= 1536;
  if (blk < 1024) { convT_body(Wq, WqT, 1024, blk, tid, Ls); return; }
  blk -= 1024;
  if (blk < 768)  { convT_body(Wk, WkvT, 768, blk, tid, Ls); return; }
  blk -= 768;
  if (blk < 768)  { convT_body(Wv, WkvT + (size_t)1024 * 768, 768, blk, tid, Ls); return; }
  blk -= 768;
  convT_body(Wo, WoT, 1024, blk, tid, Ls);
}

// ---- gemm256kv: C = CtxB[4096][768] @ WkvT[2048][768]^T, 128x256 tile,
//      8 waves (2Mx4N), ring-3 counted-vmcnt(3), dual K/V^T epilogue ----
__global__ __launch_bounds__(512) void gemm256kv(
    const ushort_t* __restrict__ A, const ushort_t* __restrict__ Bt,
    ushort_t* __restrict__ Kb, ushort_t* __restrict__ Vtb)
{
  constexpr int Kd = CTX_, NT = CTX_ / 32;     // 24 chunks
  extern __shared__ ushort_t L[];              // 3 slots x (A 4096 | B 8192)
  const int tid = threadIdx.x;
  const int lane = tid & 63, wid = tid >> 6;
  const int lr = lane & 15, lg = lane >> 4;
  const int wm = wid >> 2, wn = wid & 3;       // per-wave 64x64 output

  const int lin = (int)blockIdx.x;
  const int swz = (lin & 7) * 32 + (lin >> 3);
  const int bm = swz >> 3, bn = swz & 7;

  const int sr = tid >> 2;
  const int csrc = (tid & 3) ^ ((sr >> 1) & 3);
  const ushort_t* gA = A + (size_t)(bm * 128 + sr) * Kd + csrc * 8;
  const ushort_t* gB = Bt + (size_t)(bn * 256 + sr) * Kd + csrc * 8;
  const size_t halfB = (size_t)128 * Kd;

  f32x4 acc[4][4] = {};

#define KVSTAGE(c, slot) do { const int k0_ = (c) << 5;            \
    ushort_t* s_ = L + (slot) * 12288;                             \
    gload16(gA + k0_, s_ + tid * 8);                               \
    gload16(gB + k0_, s_ + 4096 + tid * 8);                        \
    gload16(gB + k0_ + halfB, s_ + 8192 + tid * 8);                \
  } while (0)

  KVSTAGE(0, 0); KVSTAGE(1, 1);
  int cur = 0, sls = 2;
  for (int t = 0; t < NT; ++t) {
    if (t < NT - 1) asm volatile("s_waitcnt vmcnt(3)" ::: "memory");
    else            asm volatile("s_waitcnt vmcnt(0)" ::: "memory");
    __builtin_amdgcn_s_barrier();
    __builtin_amdgcn_sched_barrier(0);
    if (t + 2 < NT) KVSTAGE(t + 2, sls);
    const ushort_t* As_ = L + cur * 12288;
    const ushort_t* Bs_ = As_ + 4096;
    short8 af[4], bf[4];
#pragma unroll
    for (int m = 0; m < 4; ++m) {
      const int row = wm * 64 + m * 16 + lr;
      af[m] = *(const short8*)&As_[row * 32 + (lg ^ ((row >> 1) & 3)) * 8];
    }
#pragma unroll
    for (int n = 0; n < 4; ++n) {
      const int row = wn * 64 + n * 16 + lr;
      bf[n] = *(const short8*)&Bs_[row * 32 + (lg ^ ((row >> 1) & 3)) * 8];
    }
    __builtin_amdgcn_s_setprio(1);
#pragma unroll
    for (int m = 0; m < 4; ++m)
#pragma unroll
      for (int n = 0; n < 4; ++n)
        acc[m][n] = __builtin_amdgcn_mfma_f32_16x16x32_bf16(af[m], bf[n], acc[m][n], 0, 0, 0);
    __builtin_amdgcn_s_setprio(0);
    cur = (cur == 2) ? 0 : cur + 1;
    sls = (sls == 2) ? 0 : sls + 1;
  }
#undef KVSTAGE

  const int row0 = bm * 128 + wm * 64 + lg * 4;
  const int col0 = bn * 256 + wn * 64 + lr;

  if (col0 < 1024) {       // K half (block-uniform: bn < 4)
#pragma unroll
    for (int m = 0; m < 4; ++m)
#pragma unroll
      for (int n = 0; n < 4; ++n) {
        const int col = col0 + n * 16;
#pragma unroll
        for (int i = 0; i < 4; ++i)
          Kb[(size_t)(row0 + m * 16 + i) * EMB_ + col] = f2b_fast(acc[m][n][i]);
      }
  } else {                 // V half -> V^T [B][H][D][S]
#pragma unroll
    for (int m = 0; m < 4; ++m) {
      const int rbase = row0 + m * 16;
      const int bb = rbase >> 10;
      const int s0 = rbase & (S_ - 1);
#pragma unroll
      for (int n = 0; n < 4; ++n) {
        const int vc = col0 + n * 16 - 1024;
        const int hh = vc >> 6, dd = vc & 63;
        us4 o;
        o.x = f2b_fast(acc[m][n][0]); o.y = f2b_fast(acc[m][n][1]);
        o.z = f2b_fast(acc[m][n][2]); o.w = f2b_fast(acc[m][n][3]);
        *(us4*)&Vtb[(((size_t)bb * H_ + hh) * D_ + dd) * S_ + s0] = o;
      }
    }
  }
}

// ---- gemm256p<EPI>: 256x256, 8 waves (2Mx4N), ring-3 x 4-phase fine
//      interleave, pure global_load_lds staging. EPI 1 = bf16*QSCALE (Q-proj),
//      EPI 3 = f32 + bias (O-proj). ----
template<int EPI>
__global__ __launch_bounds__(512) void gemm256p(
    const ushort_t* __restrict__ A, const ushort_t* __restrict__ Bt,
    void* __restrict__ Cp, const float* __restrict__ bias,
    int M, int Kd, int N)
{
  extern __shared__ ushort_t L[];   // 3 slots x 16384 ushorts (A 8192 | B 8192)
  const int tid = threadIdx.x;
  const int lane = tid & 63, wid = tid >> 6;
  const int lr = lane & 15, lg = lane >> 4;
  const int wm = wid >> 2, wn = wid & 3;

  const int cpx = (int)gridDim.x >> 3;
  const int lin = (int)blockIdx.x;
  const int swz = (lin & 7) * cpx + (lin >> 3);
  const int nbn = N >> 8;
  const int bm = swz / nbn, bn = swz % nbn;

  const int sr = tid >> 2;
  const int csrc = (tid & 3) ^ ((sr >> 1) & 3);
  const ushort_t* gA = A + (size_t)(bm * 256 + sr) * Kd + csrc * 8;
  const ushort_t* gB = Bt + (size_t)(bn * 256 + sr) * Kd + csrc * 8;
  const size_t half = (size_t)128 * Kd;

  f32x4 acc[8][4] = {};
  const int NT = Kd >> 5;

#define STAGEQ(c, q) do {                                            \
    const int k0_ = (c) << 5;                                        \
    ushort_t* s_ = L + ((c) % 3) * 16384 + (q) * 4096 + tid * 8;     \
    if ((q) == 0)      gload16(gA + k0_, s_);                        \
    else if ((q) == 1) gload16(gA + k0_ + half, s_);                 \
    else if ((q) == 2) gload16(gB + k0_, s_);                        \
    else               gload16(gB + k0_ + half, s_);                 \
  } while (0)

#pragma unroll
  for (int q = 0; q < 4; ++q) STAGEQ(0, q);
#pragma unroll
  for (int q = 0; q < 4; ++q) STAGEQ(1, q);
  asm volatile("s_waitcnt vmcnt(4)" ::: "memory");
  __builtin_amdgcn_s_barrier();
  __builtin_amdgcn_sched_barrier(0);

  for (int t = 0; t < NT; ++t) {
    const ushort_t* As_ = L + (t % 3) * 16384;
    const ushort_t* Bs_ = As_ + 8192;
    const bool st = (t + 2 < NT);
    short8 bf[4];
#pragma unroll
    for (int q = 0; q < 4; ++q) {
      if (q == 0) {
#pragma unroll
        for (int n = 0; n < 4; ++n) {
          const int row = wn * 64 + n * 16 + lr;
          bf[n] = *(const short8*)&Bs_[row * 32 + (lg ^ ((row >> 1) & 3)) * 8];
        }
      }
      const int r0 = wm * 128 + (2 * q) * 16 + lr;
      const int r1 = r0 + 16;
      const short8 af0 = *(const short8*)&As_[r0 * 32 + (lg ^ ((r0 >> 1) & 3)) * 8];
      const short8 af1 = *(const short8*)&As_[r1 * 32 + (lg ^ ((r1 >> 1) & 3)) * 8];
      if (st) STAGEQ(t + 2, q);
      __builtin_amdgcn_s_barrier();
      asm volatile("s_waitcnt lgkmcnt(0)" ::: "memory");
      __builtin_amdgcn_sched_barrier(0);
      __builtin_amdgcn_s_setprio(1);
#pragma unroll
      for (int n = 0; n < 4; ++n)
        acc[2 * q][n] = __builtin_amdgcn_mfma_f32_16x16x32_bf16(af0, bf[n], acc[2 * q][n], 0, 0, 0);
#pragma unroll
      for (int n = 0; n < 4; ++n)
        acc[2 * q + 1][n] = __builtin_amdgcn_mfma_f32_16x16x32_bf16(af1, bf[n], acc[2 * q + 1][n], 0, 0, 0);
      __builtin_amdgcn_s_setprio(0);
      if (q == 3 && t < NT - 1) {
        if (st) asm volatile("s_waitcnt vmcnt(4)" ::: "memory");
        else    asm volatile("s_waitcnt vmcnt(0)" ::: "memory");
      }
      __builtin_amdgcn_s_barrier();
      __builtin_amdgcn_sched_barrier(0);
    }
  }
#undef STAGEQ

  const int row0 = bm * 256 + wm * 128 + lg * 4;
  const int col0 = bn * 256 + wn * 64 + lr;

  if constexpr (EPI == 3) {
    float* C = (float*)Cp;
#pragma unroll
    for (int n = 0; n < 4; ++n) {
      const int col = col0 + n * 16;
      const float bv = bias[col];
#pragma unroll
      for (int m = 0; m < 8; ++m)
#pragma unroll
        for (int i = 0; i < 4; ++i)
          C[(size_t)(row0 + m * 16 + i) * N + col] = acc[m][n][i] + bv;
    }
  } else {
    ushort_t* C = (ushort_t*)Cp;
#pragma unroll
    for (int m = 0; m < 8; ++m)
#pragma unroll
      for (int n = 0; n < 4; ++n) {
        const int col = col0 + n * 16;
#pragma unroll
        for (int i = 0; i < 4; ++i)
          C[(size_t)(row0 + m * 16 + i) * N + col] = f2b(acc[m][n][i] * QSCALE);
      }
  }
}

// ---- flash attention v8 (best: 115.4 µs): QBLK=256, 8 waves x 32 rows,
//      SBLK=64, swapped QK^T, no-max exp2 softmax, l via ones-MFMA,
//      ring-3 K/V with counted vmcnt(2), shared per-wave Ps ----
__global__ __launch_bounds__(512) void attn_v8(
    const ushort_t* __restrict__ Q, const ushort_t* __restrict__ K,
    const ushort_t* __restrict__ Vt, ushort_t* __restrict__ C)
{
  extern __shared__ ushort_t SM[];
  const int tid = threadIdx.x;
  const int lane = tid & 63, w = tid >> 6;
  const int lr = lane & 15, lg = lane >> 4;

  const int bid = (int)blockIdx.x;
  const int g = (bid & 7) | (((bid >> 3) >> 4) << 3);
  const int tb = (bid >> 3) & 15;
  const int h = g & 15, b = g >> 4;
  const int t0 = tb * 256;

  short8 qf[2][2];
#pragma unroll
  for (int qs = 0; qs < 2; ++qs) {
    const size_t qrow = (size_t)b * T_ + t0 + w * 32 + qs * 16 + lr;
    const ushort_t* qp = Q + qrow * EMB_ + h * 64;
    qf[qs][0] = *(const short8*)(qp + lg * 8);
    qf[qs][1] = *(const short8*)(qp + 32 + lg * 8);
  }

  short8 ones;
#pragma unroll
  for (int j = 0; j < 8; ++j) ones[j] = (short)0x3F80;

  f32x4 o[2][4] = {};
  f32x4 lacc[2] = {};

  const int srow = tid >> 3, schunk = tid & 7;
  const int sswz = schunk ^ (srow & 7);
  const ushort_t* kg = K + ((size_t)b * S_ + srow) * EMB_ + h * 64 + sswz * 8;
  const ushort_t* vg = Vt + (((size_t)b * H_ + h) * D_ + srow) * S_ + sswz * 8;
  ushort_t* Psw = SM + 24576 + w * 1152;

  gload16(kg, SM + tid * 8);
  gload16(vg, SM + 12288 + tid * 8);
  gload16(kg + (size_t)64 * EMB_, SM + 4096 + tid * 8);
  gload16(vg + 64, SM + 12288 + 4096 + tid * 8);

  int cur = 0, sls = 2;
  for (int st = 0; st < 16; ++st) {
    if (st < 15) asm volatile("s_waitcnt vmcnt(2)" ::: "memory");
    else         asm volatile("s_waitcnt vmcnt(0)" ::: "memory");
    __builtin_amdgcn_s_barrier();
    __builtin_amdgcn_sched_barrier(0);
    if (st + 2 < 16) {
      gload16(kg + (size_t)(st + 2) * 64 * EMB_, SM + sls * 4096 + tid * 8);
      gload16(vg + (st + 2) * 64, SM + 12288 + sls * 4096 + tid * 8);
    }
    const ushort_t* Ksb = SM + cur * 4096;
    const ushort_t* Vsb = SM + 12288 + cur * 4096;

    f32x4 sacc[2][4] = {};
    __builtin_amdgcn_s_setprio(1);
#pragma unroll
    for (int c = 0; c < 4; ++c) {
      const int krow = c * 16 + lr;
      const int sw = krow & 7;
      const short8 ka0 = *(const short8*)&Ksb[krow * 64 + ((lg ^ sw) * 8)];
      const short8 ka1 = *(const short8*)&Ksb[krow * 64 + (((4 + lg) ^ sw) * 8)];
#pragma unroll
      for (int qs = 0; qs < 2; ++qs) {
        sacc[qs][c] = __builtin_amdgcn_mfma_f32_16x16x32_bf16(ka0, qf[qs][0], sacc[qs][c], 0, 0, 0);
        sacc[qs][c] = __builtin_amdgcn_mfma_f32_16x16x32_bf16(ka1, qf[qs][1], sacc[qs][c], 0, 0, 0);
      }
    }
    __builtin_amdgcn_s_setprio(0);

    short8 pa[2][2];
#pragma unroll
    for (int qs = 0; qs < 2; ++qs) {
#pragma unroll
      for (int c = 0; c < 4; ++c) {
        uint2 pk;
        pk.x = cvtpk2(exp2f(sacc[qs][c][0]), exp2f(sacc[qs][c][1]));
        pk.y = cvtpk2(exp2f(sacc[qs][c][2]), exp2f(sacc[qs][c][3]));
        *(uint2*)&Psw[lr * 72 + c * 16 + lg * 4] = pk;
      }
      pa[qs][0] = *(const short8*)&Psw[lr * 72 + lg * 8];
      pa[qs][1] = *(const short8*)&Psw[lr * 72 + 32 + lg * 8];
    }

    __builtin_amdgcn_s_setprio(1);
#pragma unroll
    for (int sh = 0; sh < 2; ++sh) {
#pragma unroll
      for (int dc = 0; dc < 4; ++dc) {
        const int vrow = dc * 16 + lr;
        const int vsw = vrow & 7;
        const short8 vb = *(const short8*)&Vsb[vrow * 64 + (((sh * 4 + lg) ^ vsw) * 8)];
        o[0][dc] = __builtin_amdgcn_mfma_f32_16x16x32_bf16(pa[0][sh], vb, o[0][dc], 0, 0, 0);
        o[1][dc] = __builtin_amdgcn_mfma_f32_16x16x32_bf16(pa[1][sh], vb, o[1][dc], 0, 0, 0);
      }
      lacc[0] = __builtin_amdgcn_mfma_f32_16x16x32_bf16(pa[0][sh], ones, lacc[0], 0, 0, 0);
      lacc[1] = __builtin_amdgcn_mfma_f32_16x16x32_bf16(pa[1][sh], ones, lacc[1], 0, 0, 0);
    }
    __builtin_amdgcn_s_setprio(0);

    cur = (cur == 2) ? 0 : cur + 1;
    sls = (sls == 2) ? 0 : sls + 1;
  }

#pragma unroll
  for (int qs = 0; qs < 2; ++qs) {
#pragma unroll
    for (int i = 0; i < 4; ++i) {
      const float li = 1.0f / lacc[qs][i];
      const size_t trow = (size_t)b * T_ + t0 + w * 32 + qs * 16 + lg * 4 + i;
#pragma unroll
      for (int dc = 0; dc < 4; ++dc)
        C[trow * EMB_ + h * 64 + dc * 16 + lr] = f2b_fast(o[qs][dc][i] * li);
    }
  }
}

extern "C" void kernel_launch(void* const* d_in, const int* in_sizes, int n_in,
                              void* d_out, int out_size, void* d_ws, size_t ws_size,
                              hipStream_t stream) {
  const float* tokens  = (const float*)d_in[0];
  const float* context = (const float*)d_in[1];
  const float* Wq = (const float*)d_in[2];
  const float* Wk = (const float*)d_in[3];
  const float* Wv = (const float*)d_in[4];
  const float* Wo = (const float*)d_in[5];
  const float* bo = (const float*)d_in[6];
  float* out = (float*)d_out;

  // d_out: Qb (lower half) + Tok (upper half) until O-proj overwrites it
  ushort_t* Qb  = (ushort_t*)d_out;
  ushort_t* Tok = Qb + (size_t)B_ * T_ * EMB_;
  // ws: Kb | Vtb | Cb (ctx bf16, then attn out) | WqT | WkvT | WoT
  ushort_t* Kb   = (ushort_t*)d_ws;
  ushort_t* Vtb  = Kb + (size_t)B_ * S_ * EMB_;
  ushort_t* Cb   = Vtb + (size_t)B_ * S_ * EMB_;
  ushort_t* WqT  = Cb + (size_t)B_ * T_ * EMB_;
  ushort_t* WkvT = WqT + (size_t)EMB_ * HID_;
  ushort_t* WoT  = WkvT + (size_t)EMB_ * 2 * CTX_;

  // 1. prep: tokens->bf16, context->bf16, Wq^T, Wk^T, Wv^T, Wo^T
  prepA<<<13312, 256, 0, stream>>>(tokens, context, Wq, Wk, Wv, Wo,
                                   Tok, Cb, WqT, WkvT, WoT);
  // 2. Q-proj (bf16 A, 4-phase ring-3, QSCALE epilogue)
  gemm256p<1><<<dim3((B_ * T_ / 256) * (EMB_ / 256)), 512, 98304, stream>>>(
      Tok, WqT, Qb, nullptr, B_ * T_, HID_, EMB_);
  // 3. fused K+V proj, 128x256 ring-3 counted-vmcnt, dual epilogue
  gemm256kv<<<dim3(256), 512, 73728, stream>>>(Cb, WkvT, Kb, Vtb);
  // 4. attention -> ctx bf16 (Cb)
  attn_v8<<<dim3((T_ / 256) * H_ * B_), 512, 67584, stream>>>(Qb, Kb, Vtb, Cb);
  // 5. O-proj + bias -> f32 out, 4-phase fine-interleaved ring-3
  gemm256p<3><<<dim3((B_ * T_ / 256) * (HID_ / 256)), 512, 98304, stream>>>(
      Cb, WoT, out, bo, B_ * T_, EMB_, HID_);
}